// Round 1
// baseline (3857.901 us; speedup 1.0000x reference)
//
#include <hip/hip_runtime.h>

typedef unsigned short u16;
typedef short bf16x8 __attribute__((ext_vector_type(8)));
typedef float f32x4 __attribute__((ext_vector_type(4)));

#define BATCH 32
#define TT 64
#define SS 64
#define VV 32000
#define EE 512
#define HH 512
#define SDD 1024

struct __align__(8) u16x4 { u16 x, y, z, w; };

__device__ __forceinline__ u16 f2bf(float f) {
    union { float f; unsigned u; } v; v.f = f;
    unsigned u = v.u;
    unsigned r = u + 0x7fffu + ((u >> 16) & 1u);
    return (u16)(r >> 16);
}
__device__ __forceinline__ float bf2f(unsigned b) {
    union { unsigned u; float f; } v; v.u = (b & 0xffffu) << 16;
    return v.f;
}
__device__ __forceinline__ float sigmoidf(float x) { return 1.0f / (1.0f + expf(-x)); }

#define GLOAD_LDS16(g, l) __builtin_amdgcn_global_load_lds( \
    (const __attribute__((address_space(1))) unsigned int*)(g), \
    (__attribute__((address_space(3))) unsigned int*)(l), 16, 0, 0)

// ---------------------------------------------------------------------------
// Generic bf16 GEMM: C(M,N) = A(M,K) * Bt(N,K)^T  (both row-major, bf16)
// mode 0: Cf[m*N+n] = acc + bias1[n] + bias2[n]        (xgates)
// mode 1: Cb[m*N+n] = bf16(acc)                        (srcWp)
// mode 2: Cf[(b*TT+t)*VV+n] = acc + bias1[n], m=t*32+b (final FC, scatter)
// 128x128 tile, BK=64, 4 waves (2x2), 16x16x32 bf16 MFMA, global_load_lds.
// ---------------------------------------------------------------------------
__global__ __launch_bounds__(256) void gemm_bt(
    const u16* __restrict__ A, const u16* __restrict__ Bt,
    float* __restrict__ Cf, u16* __restrict__ Cb,
    const float* __restrict__ bias1, const float* __restrict__ bias2,
    int M, int N, int K, int mode)
{
    __shared__ __align__(16) u16 As[128 * 64];
    __shared__ __align__(16) u16 Bs[128 * 64];
    int tid = threadIdx.x;
    int w = tid >> 6, lane = tid & 63;
    int wm = w >> 1, wn = w & 1;
    int m0 = blockIdx.y * 128, n0 = blockIdx.x * 128;

    f32x4 acc[4][4];
#pragma unroll
    for (int i = 0; i < 4; i++)
#pragma unroll
        for (int j = 0; j < 4; j++)
#pragma unroll
            for (int r = 0; r < 4; r++) acc[i][j][r] = 0.0f;

    int lrow = lane >> 3;          // 0..7
    int lcol = (lane & 7) * 8;     // element col within 64

    for (int k0 = 0; k0 < K; k0 += 64) {
#pragma unroll
        for (int i = 0; i < 4; i++) {
            int li = i * 4 + w;            // 0..15
            int row = li * 8 + lrow;       // 0..127
            const u16* ga = A + (size_t)(m0 + row) * K + k0 + lcol;
            const u16* gb = Bt + (size_t)(n0 + row) * K + k0 + lcol;
            GLOAD_LDS16(ga, As + li * 512);
            GLOAD_LDS16(gb, Bs + li * 512);
        }
        __syncthreads();
        int lm = lane & 15;
#pragma unroll
        for (int kk = 0; kk < 2; kk++) {
            int lk = kk * 32 + (lane >> 4) * 8;
            bf16x8 af[4], bfr[4];
#pragma unroll
            for (int mt = 0; mt < 4; mt++)
                af[mt] = *(const bf16x8*)(As + (wm * 64 + mt * 16 + lm) * 64 + lk);
#pragma unroll
            for (int nt = 0; nt < 4; nt++)
                bfr[nt] = *(const bf16x8*)(Bs + (wn * 64 + nt * 16 + lm) * 64 + lk);
#pragma unroll
            for (int mt = 0; mt < 4; mt++)
#pragma unroll
                for (int nt = 0; nt < 4; nt++)
                    acc[mt][nt] = __builtin_amdgcn_mfma_f32_16x16x32_bf16(
                        af[mt], bfr[nt], acc[mt][nt], 0, 0, 0);
        }
        __syncthreads();
    }

    int col = lane & 15, rowq = (lane >> 4) * 4;
#pragma unroll
    for (int mt = 0; mt < 4; mt++) {
#pragma unroll
        for (int nt = 0; nt < 4; nt++) {
            f32x4 v = acc[mt][nt];
            int gn = n0 + wn * 64 + nt * 16 + col;
            int gmb = m0 + wm * 64 + mt * 16 + rowq;
#pragma unroll
            for (int r = 0; r < 4; r++) {
                int gm = gmb + r;
                float val = v[r];
                if (mode == 0) {
                    Cf[(size_t)gm * N + gn] = val + bias1[gn] + bias2[gn];
                } else if (mode == 1) {
                    Cb[(size_t)gm * N + gn] = f2bf(val);
                } else {
                    int t = gm >> 5, b = gm & 31;
                    Cf[((size_t)b * TT + t) * VV + gn] = val + bias1[gn];
                }
            }
        }
    }
}

// ---------------------------------------------------------------------------
// Per-step LSTM: gates = xg + hhat @ W_ihH^T + h @ W_hh^T; cell update.
// grid (32 j-slices of 16, 8 b-quads of 4), 256 threads.
// ---------------------------------------------------------------------------
__global__ __launch_bounds__(256) void lstm_step(
    const float* __restrict__ xg, const float* __restrict__ W_ih,
    const float* __restrict__ W_hh,
    const float* __restrict__ h_read, const float* __restrict__ hhat_read,
    float* __restrict__ h_write, float* __restrict__ c, int t)
{
    int g = blockIdx.x;   // 0..31
    int bh = blockIdx.y;  // 0..7
    int tid = threadIdx.x;
    __shared__ __align__(16) float hs[4][516];
    __shared__ __align__(16) float hhs[4][516];
    __shared__ float gsl[4][16][4];

    for (int i = tid; i < 2048; i += 256) {
        int bi = i >> 9, k = i & 511;
        hs[bi][k] = h_read[(size_t)(bh * 4 + bi) * 512 + k];
        hhs[bi][k] = hhat_read[(size_t)(bh * 4 + bi) * 512 + k];
    }
    __syncthreads();

    int rl = tid >> 2, bl = tid & 3;
    int q = rl >> 4, jloc = rl & 15;
    int j = g * 16 + jloc;
    int r = q * 512 + j;
    int b = bh * 4 + bl;

    float acc = xg[((size_t)t * 32 + b) * 2048 + r];
    const float4* wih = (const float4*)(W_ih + (size_t)r * 1024 + 512);
    const float4* whh = (const float4*)(W_hh + (size_t)r * 512);
    const float4* hv = (const float4*)hs[bl];
    const float4* hhv = (const float4*)hhs[bl];
#pragma unroll 4
    for (int k = 0; k < 128; k++) {
        float4 w1 = wih[k], x1 = hhv[k];
        float4 w2 = whh[k], x2 = hv[k];
        acc += w1.x * x1.x + w1.y * x1.y + w1.z * x1.z + w1.w * x1.w;
        acc += w2.x * x2.x + w2.y * x2.y + w2.z * x2.z + w2.w * x2.w;
    }
    gsl[q][jloc][bl] = acc;
    __syncthreads();

    if (rl < 16) {  // tid < 64: (jloc=rl, bl)
        int jl = g * 16 + rl;
        float ig = sigmoidf(gsl[0][rl][bl]);
        float fg = sigmoidf(gsl[1][rl][bl]);
        float gg = tanhf(gsl[2][rl][bl]);
        float og = sigmoidf(gsl[3][rl][bl]);
        size_t idx = (size_t)b * 512 + jl;
        float cn = fg * c[idx] + ig * gg;
        c[idx] = cn;
        h_write[idx] = og * tanhf(cn);
    }
}

// ---------------------------------------------------------------------------
// Per-step attention + h_hat. grid (4 j-slices of 128, 32 b), 256 threads.
// ---------------------------------------------------------------------------
__global__ __launch_bounds__(256) void attn_step(
    const u16* __restrict__ srcb, const u16* __restrict__ srcWpB,
    const float* __restrict__ srcbias, const float* __restrict__ h_read,
    const u16* __restrict__ WahB, const float* __restrict__ bah,
    float* __restrict__ hhat_write, u16* __restrict__ outs, int t)
{
    int q = blockIdx.x;  // 0..3
    int b = blockIdx.y;  // 0..31
    int tid = threadIdx.x;
    __shared__ __align__(16) float cat[1536];  // [0:512)=h, [512:1536)=c_t
    __shared__ float probs[64];
    __shared__ float red[256];

    for (int i = tid; i < 512; i += 256) cat[i] = h_read[(size_t)b * 512 + i];
    __syncthreads();

    // scores: s = tid>>2, 4 chunks of 128
    {
        int s = tid >> 2, ch = tid & 3;
        const uint4* wp4 = (const uint4*)(srcWpB + ((size_t)b * 64 + s) * 512 + ch * 128);
        const float* hp = cat + ch * 128;
        float p = 0.f;
#pragma unroll 4
        for (int k8 = 0; k8 < 16; k8++) {
            uint4 wv = wp4[k8];
            const float* x = hp + k8 * 8;
            p += bf2f(wv.x) * x[0] + bf2f(wv.x >> 16) * x[1];
            p += bf2f(wv.y) * x[2] + bf2f(wv.y >> 16) * x[3];
            p += bf2f(wv.z) * x[4] + bf2f(wv.z >> 16) * x[5];
            p += bf2f(wv.w) * x[6] + bf2f(wv.w >> 16) * x[7];
        }
        red[tid] = p;
    }
    __syncthreads();
    if (tid < 64) {
        float sc = (red[tid * 4] + red[tid * 4 + 1] + red[tid * 4 + 2] + red[tid * 4 + 3]
                    + srcbias[b * 64 + tid]) * 0.04419417382415922f;  // 1/sqrt(512)
        float m = sc;
        for (int off = 32; off; off >>= 1) m = fmaxf(m, __shfl_xor(m, off));
        float e = expf(sc - m);
        float sum = e;
        for (int off = 32; off; off >>= 1) sum += __shfl_xor(sum, off);
        probs[tid] = e / sum;
    }
    __syncthreads();

    // c_t[d] = sum_s probs[s] * src[b,s,d]
    for (int d = tid; d < 1024; d += 256) {
        float a = 0.f;
        const u16* sp = srcb + (size_t)b * 65536 + d;
#pragma unroll 8
        for (int s2 = 0; s2 < 64; s2++) a += probs[s2] * bf2f(sp[s2 * 1024]);
        cat[512 + d] = a;
    }
    __syncthreads();

    // h_hat rows j in [q*128, q*128+128), 2 threads per j (768 each)
    int j = q * 128 + (tid >> 1), half = tid & 1;
    const uint4* w8 = (const uint4*)(WahB + (size_t)j * 1536 + half * 768);
    const float* xv = cat + half * 768;
    float a = 0.f;
#pragma unroll 4
    for (int k8 = 0; k8 < 96; k8++) {
        uint4 wv = w8[k8];
        const float* x = xv + k8 * 8;
        a += bf2f(wv.x) * x[0] + bf2f(wv.x >> 16) * x[1];
        a += bf2f(wv.y) * x[2] + bf2f(wv.y >> 16) * x[3];
        a += bf2f(wv.z) * x[4] + bf2f(wv.z >> 16) * x[5];
        a += bf2f(wv.w) * x[6] + bf2f(wv.w >> 16) * x[7];
    }
    a += __shfl_xor(a, 1);
    if (half == 0) {
        float v = tanhf(a + bah[j]);
        hhat_write[(size_t)b * 512 + j] = v;
        outs[((size_t)t * 32 + b) * 512 + j] = f2bf(v);
    }
}

// ---------------------------------------------------------------------------
// Prep kernels
// ---------------------------------------------------------------------------
__global__ void conv_f2b4(const float* __restrict__ in, u16* __restrict__ out, int n4) {
    int i = blockIdx.x * 256 + threadIdx.x;
    if (i < n4) {
        float4 v = ((const float4*)in)[i];
        u16x4 o; o.x = f2bf(v.x); o.y = f2bf(v.y); o.z = f2bf(v.z); o.w = f2bf(v.w);
        *(u16x4*)(out + (size_t)i * 4) = o;
    }
}

__global__ void conv_wihx(const float* __restrict__ W_ih, u16* __restrict__ out) {
    int i = blockIdx.x * 256 + threadIdx.x;  // 2048 rows * 128 float4
    int r = i >> 7, k4 = i & 127;
    float4 v = ((const float4*)(W_ih + (size_t)r * 1024))[k4];
    u16x4 o; o.x = f2bf(v.x); o.y = f2bf(v.y); o.z = f2bf(v.z); o.w = f2bf(v.w);
    *(u16x4*)(out + (size_t)r * 512 + k4 * 4) = o;
}

__global__ void gather_emb(const int* __restrict__ trg, const float* __restrict__ emb,
                           u16* __restrict__ X) {
    int m = blockIdx.x;  // t*32+b
    int t = m >> 5, b = m & 31;
    int v = trg[b * 64 + t];
    const float4* e4 = (const float4*)(emb + (size_t)v * 512);
    int tid = threadIdx.x;  // 128
    float4 x = e4[tid];
    u16x4 o; o.x = f2bf(x.x); o.y = f2bf(x.y); o.z = f2bf(x.z); o.w = f2bf(x.w);
    *(u16x4*)(X + (size_t)m * 512 + tid * 4) = o;
}

__global__ void transpose_wp(const float* __restrict__ Wp, u16* __restrict__ WpT) {
    int i = blockIdx.x * 256 + threadIdx.x;  // 512*1024
    int k = i >> 10, d = i & 1023;
    WpT[i] = f2bf(Wp[(size_t)d * 512 + k]);
}

__global__ void srcbias_k(const float* __restrict__ src, const float* __restrict__ bp,
                          float* __restrict__ sb) {
    int bs = blockIdx.x;
    int tid = threadIdx.x;  // 256, exactly 256 float4 = 1024 floats
    const float4* s4 = (const float4*)(src + (size_t)bs * 1024);
    const float4* b4 = (const float4*)bp;
    float4 a = s4[tid], w = b4[tid];
    float p = a.x * w.x + a.y * w.y + a.z * w.z + a.w * w.w;
    for (int off = 32; off; off >>= 1) p += __shfl_xor(p, off);
    __shared__ float r4[4];
    if ((tid & 63) == 0) r4[tid >> 6] = p;
    __syncthreads();
    if (tid == 0) sb[bs] = r4[0] + r4[1] + r4[2] + r4[3];
}

__global__ void init_state(const float* __restrict__ hid, const float* __restrict__ iff,
                           float* __restrict__ h0, float* __restrict__ c0,
                           float* __restrict__ hh0) {
    int i = blockIdx.x * 256 + threadIdx.x;  // 16384
    int j = i & 511;
    h0[i] = hid[j];
    c0[i] = hid[512 + j];
    hh0[i] = iff[j];
}

__global__ void tail_copy(const float* __restrict__ hf, const float* __restrict__ cf,
                          const float* __restrict__ hhf, float* __restrict__ out) {
    int i = blockIdx.x * 256 + threadIdx.x;  // 16384
    out[65536000 + i] = hf[i];
    out[65536000 + 16384 + i] = cf[i];
    out[65536000 + 32768 + i] = hhf[i];
}

// ---------------------------------------------------------------------------
extern "C" void kernel_launch(void* const* d_in, const int* in_sizes, int n_in,
                              void* d_out, int out_size, void* d_ws, size_t ws_size,
                              hipStream_t stream) {
    (void)in_sizes; (void)n_in; (void)out_size; (void)ws_size;
    const float* src = (const float*)d_in[0];
    const int* trg = (const int*)d_in[1];
    const float* emb = (const float*)d_in[2];
    const float* W_ih = (const float*)d_in[3];
    const float* b_ih = (const float*)d_in[4];
    const float* W_hh = (const float*)d_in[5];
    const float* b_hh = (const float*)d_in[6];
    const float* Wp = (const float*)d_in[7];
    const float* bp = (const float*)d_in[8];
    const float* Wah = (const float*)d_in[9];
    const float* bah = (const float*)d_in[10];
    const float* Wfc = (const float*)d_in[11];
    const float* bfc = (const float*)d_in[12];
    const float* iff = (const float*)d_in[13];
    const float* hid = (const float*)d_in[14];
    float* out = (float*)d_out;

    char* wsb = (char*)d_ws;
    size_t off = 0;
    auto alloc = [&](size_t bytes) {
        void* p = wsb + off;
        off += (bytes + 255) & ~(size_t)255;
        return p;
    };
    float* xgates  = (float*)alloc(2048UL * 2048 * 4);   // [t*32+b][2048]
    u16*   srcWpB  = (u16*)  alloc(2048UL * 512 * 2);    // [b*64+s][512]
    float* srcbias = (float*)alloc(2048UL * 4);
    float* hbuf0   = (float*)alloc(16384UL * 4);
    float* hbuf1   = (float*)alloc(16384UL * 4);
    float* cbuf    = (float*)alloc(16384UL * 4);
    float* hhat0b  = (float*)alloc(16384UL * 4);
    float* hhat1b  = (float*)alloc(16384UL * 4);
    u16*   outsB   = (u16*)  alloc(2048UL * 512 * 2);    // [t*32+b][512]
    u16*   Xemb    = (u16*)  alloc(2048UL * 512 * 2);
    u16*   WihX    = (u16*)  alloc(2048UL * 512 * 2);
    u16*   WpT     = (u16*)  alloc(512UL * 1024 * 2);
    u16*   srcB    = (u16*)  alloc(2048UL * 1024 * 2);
    u16*   WahB    = (u16*)  alloc(512UL * 1536 * 2);
    u16*   WfcB    = (u16*)  alloc(32000UL * 512 * 2);

    // prep / conversions
    conv_f2b4<<<2048, 256, 0, stream>>>(src, srcB, 524288);
    conv_f2b4<<<768, 256, 0, stream>>>(Wah, WahB, 196608);
    conv_f2b4<<<16000, 256, 0, stream>>>(Wfc, WfcB, 4096000);
    conv_wihx<<<1024, 256, 0, stream>>>(W_ih, WihX);
    gather_emb<<<2048, 128, 0, stream>>>(trg, emb, Xemb);
    transpose_wp<<<2048, 256, 0, stream>>>(Wp, WpT);
    srcbias_k<<<2048, 256, 0, stream>>>(src, bp, srcbias);
    init_state<<<64, 256, 0, stream>>>(hid, iff, hbuf0, cbuf, hhat0b);

    // hoisted GEMMs
    gemm_bt<<<dim3(16, 16), 256, 0, stream>>>(Xemb, WihX, xgates, nullptr,
                                              b_ih, b_hh, 2048, 2048, 512, 0);
    gemm_bt<<<dim3(4, 16), 256, 0, stream>>>(srcB, WpT, nullptr, srcWpB,
                                             nullptr, nullptr, 2048, 512, 1024, 1);

    // sequential recurrence
    float* hb[2] = {hbuf0, hbuf1};
    float* hhb[2] = {hhat0b, hhat1b};
    for (int t = 0; t < 64; t++) {
        int p = t & 1, pn = p ^ 1;
        lstm_step<<<dim3(32, 8), 256, 0, stream>>>(xgates, W_ih, W_hh,
                                                   hb[p], hhb[p], hb[pn], cbuf, t);
        attn_step<<<dim3(4, 32), 256, 0, stream>>>(srcB, srcWpB, srcbias,
                                                   hb[pn], WahB, bah, hhb[pn], outsB, t);
    }

    // final projection + state outputs
    gemm_bt<<<dim3(250, 16), 256, 0, stream>>>(outsB, WfcB, out, nullptr,
                                               bfc, nullptr, 2048, 32000, 512, 2);
    tail_copy<<<64, 256, 0, stream>>>(hb[0], cbuf, hhb[0], out);
}

// Round 2
// 2884.752 us; speedup vs baseline: 1.3373x; 1.3373x over previous
//
#include <hip/hip_runtime.h>

typedef unsigned short u16;
typedef short bf16x8 __attribute__((ext_vector_type(8)));
typedef float f32x4 __attribute__((ext_vector_type(4)));

struct __align__(8) u16x4s { u16 x, y, z, w; };

__device__ __forceinline__ u16 f2bf(float f) {
    union { float f; unsigned u; } v; v.f = f;
    unsigned u = v.u;
    unsigned r = u + 0x7fffu + ((u >> 16) & 1u);
    return (u16)(r >> 16);
}
__device__ __forceinline__ float bf2f(unsigned b) {
    union { unsigned u; float f; } v; v.u = (b & 0xffffu) << 16;
    return v.f;
}
__device__ __forceinline__ float sigmoidf(float x) { return 1.0f / (1.0f + expf(-x)); }

#define GLOAD_LDS16(g, l) __builtin_amdgcn_global_load_lds( \
    (const __attribute__((address_space(1))) unsigned int*)(g), \
    (__attribute__((address_space(3))) unsigned int*)(l), 16, 0, 0)

// ---------------------------------------------------------------------------
// bf16 GEMM: C(M,N) = A(M,K) * Bt(N,K)^T
// mode 0: xgates -> permuted xg2[t][g][rr][b] layout + b_ih + b_hh
// mode 1: Cb[m*N+n] = bf16(acc)   (srcWp)
// ---------------------------------------------------------------------------
__global__ __launch_bounds__(256) void gemm_bt(
    const u16* __restrict__ A, const u16* __restrict__ Bt,
    float* __restrict__ Cf, u16* __restrict__ Cb,
    const float* __restrict__ bias1, const float* __restrict__ bias2,
    int M, int N, int K, int mode)
{
    __shared__ __align__(16) u16 As[128 * 64];
    __shared__ __align__(16) u16 Bs[128 * 64];
    int tid = threadIdx.x;
    int w = tid >> 6, lane = tid & 63;
    int wm = w >> 1, wn = w & 1;
    int m0 = blockIdx.y * 128, n0 = blockIdx.x * 128;

    f32x4 acc[4][4];
#pragma unroll
    for (int i = 0; i < 4; i++)
#pragma unroll
        for (int j = 0; j < 4; j++)
#pragma unroll
            for (int r = 0; r < 4; r++) acc[i][j][r] = 0.0f;

    int lrow = lane >> 3;
    int lcol = (lane & 7) * 8;

    for (int k0 = 0; k0 < K; k0 += 64) {
#pragma unroll
        for (int i = 0; i < 4; i++) {
            int li = i * 4 + w;
            int row = li * 8 + lrow;
            const u16* ga = A + (size_t)(m0 + row) * K + k0 + lcol;
            const u16* gb = Bt + (size_t)(n0 + row) * K + k0 + lcol;
            GLOAD_LDS16(ga, As + li * 512);
            GLOAD_LDS16(gb, Bs + li * 512);
        }
        __syncthreads();
        int lm = lane & 15;
#pragma unroll
        for (int kk = 0; kk < 2; kk++) {
            int lk = kk * 32 + (lane >> 4) * 8;
            bf16x8 af[4], bfr[4];
#pragma unroll
            for (int mt = 0; mt < 4; mt++)
                af[mt] = *(const bf16x8*)(As + (wm * 64 + mt * 16 + lm) * 64 + lk);
#pragma unroll
            for (int nt = 0; nt < 4; nt++)
                bfr[nt] = *(const bf16x8*)(Bs + (wn * 64 + nt * 16 + lm) * 64 + lk);
#pragma unroll
            for (int mt = 0; mt < 4; mt++)
#pragma unroll
                for (int nt = 0; nt < 4; nt++)
                    acc[mt][nt] = __builtin_amdgcn_mfma_f32_16x16x32_bf16(
                        af[mt], bfr[nt], acc[mt][nt], 0, 0, 0);
        }
        __syncthreads();
    }

    int col = lane & 15, rowq = (lane >> 4) * 4;
#pragma unroll
    for (int mt = 0; mt < 4; mt++) {
#pragma unroll
        for (int nt = 0; nt < 4; nt++) {
            f32x4 v = acc[mt][nt];
            int gn = n0 + wn * 64 + nt * 16 + col;
            int gmb = m0 + wm * 64 + mt * 16 + rowq;
#pragma unroll
            for (int r = 0; r < 4; r++) {
                int gm = gmb + r;
                float val = v[r];
                if (mode == 0) {
                    // gm = t*32+b, gn = gate row = q*512 + g*4 + jl
                    int t = gm >> 5, b = gm & 31;
                    int q = gn >> 9, g = (gn & 511) >> 2, jl = gn & 3;
                    Cf[(((size_t)t * 128 + g) * 16 + q * 4 + jl) * 32 + b] =
                        val + bias1[gn] + bias2[gn];
                } else {
                    Cb[(size_t)gm * N + gn] = f2bf(val);
                }
            }
        }
    }
}

// ---------------------------------------------------------------------------
// FC GEMM: out[(b*64+t)*32000+n] = outs(bf16, m=t*32+b) @ Wfc(fp32)^T + bfc
// n-outer grid (16,250) -> Wfc swept once. B converted fp32->bf16 in staging.
// ---------------------------------------------------------------------------
__global__ __launch_bounds__(256) void gemm_fc(
    const u16* __restrict__ A, const float* __restrict__ Bf,
    float* __restrict__ out, const float* __restrict__ bfc)
{
    __shared__ __align__(16) u16 As[128 * 64];
    __shared__ __align__(16) u16 Bs[128 * 64];
    int tid = threadIdx.x;
    int w = tid >> 6, lane = tid & 63;
    int wm = w >> 1, wn = w & 1;
    int m0 = blockIdx.x * 128, n0 = blockIdx.y * 128;

    f32x4 acc[4][4];
#pragma unroll
    for (int i = 0; i < 4; i++)
#pragma unroll
        for (int j = 0; j < 4; j++)
#pragma unroll
            for (int r = 0; r < 4; r++) acc[i][j][r] = 0.0f;

    int lrow = lane >> 3;
    int lcol = (lane & 7) * 8;

    for (int k0 = 0; k0 < 512; k0 += 64) {
#pragma unroll
        for (int i = 0; i < 4; i++) {
            int li = i * 4 + w;
            int row = li * 8 + lrow;
            GLOAD_LDS16(A + (size_t)(m0 + row) * 512 + k0 + lcol, As + li * 512);
        }
#pragma unroll
        for (int it = 0; it < 8; it++) {
            int idx = it * 256 + tid;       // 0..2047
            int brow = idx >> 4, c4 = idx & 15;
            float4 v = *(const float4*)(Bf + (size_t)(n0 + brow) * 512 + k0 + c4 * 4);
            u16x4s o; o.x = f2bf(v.x); o.y = f2bf(v.y); o.z = f2bf(v.z); o.w = f2bf(v.w);
            *(u16x4s*)(Bs + brow * 64 + c4 * 4) = o;
        }
        __syncthreads();
        int lm = lane & 15;
#pragma unroll
        for (int kk = 0; kk < 2; kk++) {
            int lk = kk * 32 + (lane >> 4) * 8;
            bf16x8 af[4], bfr[4];
#pragma unroll
            for (int mt = 0; mt < 4; mt++)
                af[mt] = *(const bf16x8*)(As + (wm * 64 + mt * 16 + lm) * 64 + lk);
#pragma unroll
            for (int nt = 0; nt < 4; nt++)
                bfr[nt] = *(const bf16x8*)(Bs + (wn * 64 + nt * 16 + lm) * 64 + lk);
#pragma unroll
            for (int mt = 0; mt < 4; mt++)
#pragma unroll
                for (int nt = 0; nt < 4; nt++)
                    acc[mt][nt] = __builtin_amdgcn_mfma_f32_16x16x32_bf16(
                        af[mt], bfr[nt], acc[mt][nt], 0, 0, 0);
        }
        __syncthreads();
    }

    int col = lane & 15, rowq = (lane >> 4) * 4;
#pragma unroll
    for (int mt = 0; mt < 4; mt++) {
#pragma unroll
        for (int nt = 0; nt < 4; nt++) {
            f32x4 v = acc[mt][nt];
            int gn = n0 + wn * 64 + nt * 16 + col;
            int gmb = m0 + wm * 64 + mt * 16 + rowq;
#pragma unroll
            for (int r = 0; r < 4; r++) {
                int gm = gmb + r;
                int t = gm >> 5, b = gm & 31;
                out[((size_t)b * 64 + t) * 32000 + gn] = v[r] + bfc[gn];
            }
        }
    }
}

// ---------------------------------------------------------------------------
// Per-step LSTM via MFMA. 128 WGs; WG g owns hidden units g*4..g*4+3
// (16 gate rows). A = Astate[32][1024] bf16 ([hhat|h]), B = Wcat rows,
// both fragments loaded directly from global. k split over 4 waves.
// ---------------------------------------------------------------------------
__global__ __launch_bounds__(256) void lstm_mfma(
    const u16* __restrict__ Wcat, const u16* __restrict__ As_in,
    const float* __restrict__ xg2, float* __restrict__ cbuf,
    float* __restrict__ h_f32, u16* __restrict__ As_out, int t)
{
    __shared__ float red[4][2][16][20];
    int tid = threadIdx.x;
    int w = tid >> 6, lane = tid & 63;
    int g = blockIdx.x;

    f32x4 acc0, acc1;
#pragma unroll
    for (int r = 0; r < 4; r++) { acc0[r] = 0.0f; acc1[r] = 0.0f; }

    int m16 = lane & 15;
    int koff = (lane >> 4) * 8;
    int rr = lane & 15;
    int brow = (rr >> 2) * 512 + g * 4 + (rr & 3);
    const u16* bptr = Wcat + (size_t)brow * 1024 + w * 256 + koff;
    const u16* ap0 = As_in + (size_t)m16 * 1024 + w * 256 + koff;
    const u16* ap1 = As_in + (size_t)(m16 + 16) * 1024 + w * 256 + koff;

#pragma unroll
    for (int kk = 0; kk < 8; kk++) {
        bf16x8 bf = *(const bf16x8*)(bptr + kk * 32);
        bf16x8 a0 = *(const bf16x8*)(ap0 + kk * 32);
        bf16x8 a1 = *(const bf16x8*)(ap1 + kk * 32);
        acc0 = __builtin_amdgcn_mfma_f32_16x16x32_bf16(a0, bf, acc0, 0, 0, 0);
        acc1 = __builtin_amdgcn_mfma_f32_16x16x32_bf16(a1, bf, acc1, 0, 0, 0);
    }
    // C layout: col(lane&15)=B row index rr, rows (lane>>4)*4+r = A row (b local)
    *(f32x4*)&red[w][0][lane & 15][(lane >> 4) * 4] = acc0;
    *(f32x4*)&red[w][1][lane & 15][(lane >> 4) * 4] = acc1;
    __syncthreads();

    if (tid < 128) {
        int b = tid & 31, jl = tid >> 5;
        int mt = b >> 4, ml = b & 15;
        float gv[4];
#pragma unroll
        for (int q = 0; q < 4; q++) {
            int r2 = q * 4 + jl;
            float s = red[0][mt][r2][ml] + red[1][mt][r2][ml]
                    + red[2][mt][r2][ml] + red[3][mt][r2][ml];
            gv[q] = s + xg2[(((size_t)t * 128 + g) * 16 + r2) * 32 + b];
        }
        float ig = sigmoidf(gv[0]);
        float fg = sigmoidf(gv[1]);
        float gg = tanhf(gv[2]);
        float og = sigmoidf(gv[3]);
        int j = g * 4 + jl;
        size_t ci = (size_t)b * 512 + j;
        float cn = fg * cbuf[ci] + ig * gg;
        cbuf[ci] = cn;
        float hv = og * tanhf(cn);
        h_f32[ci] = hv;
        As_out[(size_t)b * 1024 + 512 + j] = f2bf(hv);
    }
}

// ---------------------------------------------------------------------------
// Per-step attention + h_hat. grid (8 q-slices, 32 b). Each WG redundantly
// computes scores/softmax/ctx for its b, then 64 Wah rows.
// ---------------------------------------------------------------------------
__global__ __launch_bounds__(256) void attn_hhat(
    const u16* __restrict__ srcb, const u16* __restrict__ srcWpB,
    const float* __restrict__ srcbias, const float* __restrict__ h_f32,
    const u16* __restrict__ WahB, const float* __restrict__ bah,
    float* __restrict__ hhat_f32, u16* __restrict__ As_out,
    u16* __restrict__ outs, int t)
{
    int q = blockIdx.x;
    int b = blockIdx.y;
    int tid = threadIdx.x;
    __shared__ __align__(16) float cat[1536];
    __shared__ float probs[64];
    __shared__ float red2[256];

    for (int i = tid; i < 512; i += 256) cat[i] = h_f32[(size_t)b * 512 + i];
    __syncthreads();

    {
        int s = tid >> 2, ch = tid & 3;
        const uint4* wp4 = (const uint4*)(srcWpB + ((size_t)b * 64 + s) * 512 + ch * 128);
        const float* hp = cat + ch * 128;
        float p = 0.f;
#pragma unroll 4
        for (int k8 = 0; k8 < 16; k8++) {
            uint4 wv = wp4[k8];
            const float* x = hp + k8 * 8;
            p += bf2f(wv.x) * x[0] + bf2f(wv.x >> 16) * x[1];
            p += bf2f(wv.y) * x[2] + bf2f(wv.y >> 16) * x[3];
            p += bf2f(wv.z) * x[4] + bf2f(wv.z >> 16) * x[5];
            p += bf2f(wv.w) * x[6] + bf2f(wv.w >> 16) * x[7];
        }
        red2[tid] = p;
    }
    __syncthreads();
    if (tid < 64) {
        float sc = (red2[tid * 4] + red2[tid * 4 + 1] + red2[tid * 4 + 2] + red2[tid * 4 + 3]
                    + srcbias[b * 64 + tid]) * 0.04419417382415922f;
        float m = sc;
        for (int off = 32; off; off >>= 1) m = fmaxf(m, __shfl_xor(m, off));
        float e = expf(sc - m);
        float sum = e;
        for (int off = 32; off; off >>= 1) sum += __shfl_xor(sum, off);
        probs[tid] = e / sum;
    }
    __syncthreads();

    for (int d = tid; d < 1024; d += 256) {
        float a = 0.f;
        const u16* sp = srcb + (size_t)b * 65536 + d;
#pragma unroll 8
        for (int s2 = 0; s2 < 64; s2++) a += probs[s2] * bf2f(sp[s2 * 1024]);
        cat[512 + d] = a;
    }
    __syncthreads();

    int jj = tid >> 2, part = tid & 3;
    int j = q * 64 + jj;
    const uint4* w8 = (const uint4*)(WahB + (size_t)j * 1536 + part * 384);
    const float* xv = cat + part * 384;
    float a0 = 0.f, a1 = 0.f, a2 = 0.f, a3 = 0.f;
#pragma unroll 4
    for (int k8 = 0; k8 < 48; k8++) {
        uint4 wv = w8[k8];
        const float* x = xv + k8 * 8;
        a0 += bf2f(wv.x) * x[0] + bf2f(wv.x >> 16) * x[1];
        a1 += bf2f(wv.y) * x[2] + bf2f(wv.y >> 16) * x[3];
        a2 += bf2f(wv.z) * x[4] + bf2f(wv.z >> 16) * x[5];
        a3 += bf2f(wv.w) * x[6] + bf2f(wv.w >> 16) * x[7];
    }
    float a = (a0 + a1) + (a2 + a3);
    a += __shfl_xor(a, 1);
    a += __shfl_xor(a, 2);
    if (part == 0) {
        float v = tanhf(a + bah[j]);
        hhat_f32[(size_t)b * 512 + j] = v;
        As_out[(size_t)b * 1024 + j] = f2bf(v);
        outs[((size_t)t * 32 + b) * 512 + j] = f2bf(v);
    }
}

// ---------------------------------------------------------------------------
// Prep kernels
// ---------------------------------------------------------------------------
__global__ void conv_f2b4(const float* __restrict__ in, u16* __restrict__ out, int n4) {
    int i = blockIdx.x * 256 + threadIdx.x;
    if (i < n4) {
        float4 v = ((const float4*)in)[i];
        u16x4s o; o.x = f2bf(v.x); o.y = f2bf(v.y); o.z = f2bf(v.z); o.w = f2bf(v.w);
        *(u16x4s*)(out + (size_t)i * 4) = o;
    }
}

__global__ void conv_wihx(const float* __restrict__ W_ih, u16* __restrict__ out) {
    int i = blockIdx.x * 256 + threadIdx.x;  // 2048 rows * 128 float4
    int r = i >> 7, k4 = i & 127;
    float4 v = ((const float4*)(W_ih + (size_t)r * 1024))[k4];
    u16x4s o; o.x = f2bf(v.x); o.y = f2bf(v.y); o.z = f2bf(v.z); o.w = f2bf(v.w);
    *(u16x4s*)(out + (size_t)r * 512 + k4 * 4) = o;
}

__global__ void conv_wcat(const float* __restrict__ W_ih, const float* __restrict__ W_hh,
                          u16* __restrict__ Wcat) {
    int i = blockIdx.x * 256 + threadIdx.x;  // 2048 * 256
    int r = i >> 8, c4 = i & 255;
    int col = c4 * 4;
    const float* src = (col < 512) ? (W_ih + (size_t)r * 1024 + 512 + col)
                                   : (W_hh + (size_t)r * 512 + (col - 512));
    float4 v = *(const float4*)src;
    u16x4s o; o.x = f2bf(v.x); o.y = f2bf(v.y); o.z = f2bf(v.z); o.w = f2bf(v.w);
    *(u16x4s*)(Wcat + (size_t)r * 1024 + col) = o;
}

__global__ void gather_emb(const int* __restrict__ trg, const float* __restrict__ emb,
                           u16* __restrict__ X) {
    int m = blockIdx.x;  // t*32+b
    int t = m >> 5, b = m & 31;
    int v = trg[b * 64 + t];
    const float4* e4 = (const float4*)(emb + (size_t)v * 512);
    int tid = threadIdx.x;  // 128
    float4 x = e4[tid];
    u16x4s o; o.x = f2bf(x.x); o.y = f2bf(x.y); o.z = f2bf(x.z); o.w = f2bf(x.w);
    *(u16x4s*)(X + (size_t)m * 512 + tid * 4) = o;
}

__global__ void transpose_wp(const float* __restrict__ Wp, u16* __restrict__ WpT) {
    int i = blockIdx.x * 256 + threadIdx.x;  // 512*1024
    int k = i >> 10, d = i & 1023;
    WpT[i] = f2bf(Wp[(size_t)d * 512 + k]);
}

__global__ void srcbias_k(const float* __restrict__ src, const float* __restrict__ bp,
                          float* __restrict__ sb) {
    int bs = blockIdx.x;
    int tid = threadIdx.x;
    const float4* s4 = (const float4*)(src + (size_t)bs * 1024);
    const float4* b4 = (const float4*)bp;
    float4 a = s4[tid], w = b4[tid];
    float p = a.x * w.x + a.y * w.y + a.z * w.z + a.w * w.w;
    for (int off = 32; off; off >>= 1) p += __shfl_xor(p, off);
    __shared__ float r4[4];
    if ((tid & 63) == 0) r4[tid >> 6] = p;
    __syncthreads();
    if (tid == 0) sb[bs] = r4[0] + r4[1] + r4[2] + r4[3];
}

__global__ void init_state2(const float* __restrict__ hid, const float* __restrict__ iff,
                            u16* __restrict__ As0, float* __restrict__ c0) {
    int i = blockIdx.x * 256 + threadIdx.x;  // 32768
    int k = i & 1023;
    As0[i] = f2bf(k < 512 ? iff[k] : hid[k - 512]);
    if (i < 16384) c0[i] = hid[512 + (i & 511)];
}

__global__ void tail_copy(const float* __restrict__ hf, const float* __restrict__ cf,
                          const float* __restrict__ hhf, float* __restrict__ out) {
    int i = blockIdx.x * 256 + threadIdx.x;  // 16384
    out[65536000 + i] = hf[i];
    out[65536000 + 16384 + i] = cf[i];
    out[65536000 + 32768 + i] = hhf[i];
}

// ---------------------------------------------------------------------------
extern "C" void kernel_launch(void* const* d_in, const int* in_sizes, int n_in,
                              void* d_out, int out_size, void* d_ws, size_t ws_size,
                              hipStream_t stream) {
    (void)in_sizes; (void)n_in; (void)out_size; (void)ws_size;
    const float* src = (const float*)d_in[0];
    const int* trg = (const int*)d_in[1];
    const float* emb = (const float*)d_in[2];
    const float* W_ih = (const float*)d_in[3];
    const float* b_ih = (const float*)d_in[4];
    const float* W_hh = (const float*)d_in[5];
    const float* b_hh = (const float*)d_in[6];
    const float* Wp = (const float*)d_in[7];
    const float* bp = (const float*)d_in[8];
    const float* Wah = (const float*)d_in[9];
    const float* bah = (const float*)d_in[10];
    const float* Wfc = (const float*)d_in[11];
    const float* bfc = (const float*)d_in[12];
    const float* iff = (const float*)d_in[13];
    const float* hid = (const float*)d_in[14];
    float* out = (float*)d_out;

    char* wsb = (char*)d_ws;
    size_t off = 0;
    auto alloc = [&](size_t bytes) {
        void* p = wsb + off;
        off += (bytes + 255) & ~(size_t)255;
        return p;
    };
    float* xg2     = (float*)alloc(2048UL * 2048 * 4);   // [t][g][rr][b]
    u16*   srcWpB  = (u16*)  alloc(2048UL * 512 * 2);    // [b*64+s][512]
    float* srcbias = (float*)alloc(2048UL * 4);
    float* cbuf    = (float*)alloc(16384UL * 4);
    float* h_f32   = (float*)alloc(16384UL * 4);
    float* hh_f32  = (float*)alloc(16384UL * 4);
    u16*   A0      = (u16*)  alloc(32UL * 1024 * 2);     // state [hhat|h] bf16
    u16*   A1      = (u16*)  alloc(32UL * 1024 * 2);
    u16*   outsB   = (u16*)  alloc(2048UL * 512 * 2);    // [t*32+b][512]
    u16*   Xemb    = (u16*)  alloc(2048UL * 512 * 2);
    u16*   WihX    = (u16*)  alloc(2048UL * 512 * 2);
    u16*   Wcat    = (u16*)  alloc(2048UL * 1024 * 2);   // [hhat-part | W_hh]
    u16*   WpT     = (u16*)  alloc(512UL * 1024 * 2);
    u16*   srcB    = (u16*)  alloc(2048UL * 1024 * 2);
    u16*   WahB    = (u16*)  alloc(512UL * 1536 * 2);

    // prep / conversions
    conv_f2b4<<<2048, 256, 0, stream>>>(src, srcB, 524288);
    conv_f2b4<<<768, 256, 0, stream>>>(Wah, WahB, 196608);
    conv_wihx<<<1024, 256, 0, stream>>>(W_ih, WihX);
    conv_wcat<<<2048, 256, 0, stream>>>(W_ih, W_hh, Wcat);
    gather_emb<<<2048, 128, 0, stream>>>(trg, emb, Xemb);
    transpose_wp<<<2048, 256, 0, stream>>>(Wp, WpT);
    srcbias_k<<<2048, 256, 0, stream>>>(src, bp, srcbias);
    init_state2<<<128, 256, 0, stream>>>(hid, iff, A0, cbuf);

    // hoisted GEMMs
    gemm_bt<<<dim3(16, 16), 256, 0, stream>>>(Xemb, WihX, xg2, nullptr,
                                              b_ih, b_hh, 2048, 2048, 512, 0);
    gemm_bt<<<dim3(4, 16), 256, 0, stream>>>(srcB, WpT, nullptr, srcWpB,
                                             nullptr, nullptr, 2048, 512, 1024, 1);

    // sequential recurrence (ping-pong state buffers)
    u16* Ab[2] = {A0, A1};
    for (int t = 0; t < 64; t++) {
        u16* Ain = Ab[t & 1];
        u16* Aout = Ab[(t + 1) & 1];
        lstm_mfma<<<128, 256, 0, stream>>>(Wcat, Ain, xg2, cbuf, h_f32, Aout, t);
        attn_hhat<<<dim3(8, 32), 256, 0, stream>>>(srcB, srcWpB, srcbias, h_f32,
                                                   WahB, bah, hh_f32, Aout, outsB, t);
    }

    // final projection (Wfc consumed fp32 directly, n-outer sweep) + states
    gemm_fc<<<dim3(16, 250), 256, 0, stream>>>(outsB, Wfc, out, bfc);
    tail_copy<<<64, 256, 0, stream>>>(h_f32, cbuf, hh_f32, out);
}